// Round 19
// baseline (114.222 us; speedup 1.0000x reference)
//
#include <hip/hip_runtime.h>

typedef int   i32x4 __attribute__((ext_vector_type(4)));
typedef float f32x4 __attribute__((ext_vector_type(4)));

#define QMAXF 127.0f
#define BAR()   __builtin_amdgcn_s_barrier()
#define LGKM0() asm volatile("s_waitcnt lgkmcnt(0)" ::: "memory")

// ---------------------------------------------------------------------------
// Weight quantization: one block per output row (cout). ~2 us. Proven R3-R17.
// ---------------------------------------------------------------------------
__global__ __launch_bounds__(256) void quant_w_kernel(
    const float* __restrict__ w, const float* __restrict__ act_scale,
    signed char* __restrict__ qw, float* __restrict__ wscale)
{
    const int row = blockIdx.x;
    const int t   = threadIdx.x;
    const float s = act_scale[0];

    float4 v = *reinterpret_cast<const float4*>(w + (size_t)row * 1024 + t * 4);
    float a0 = v.x * s, a1 = v.y * s, a2 = v.z * s, a3 = v.w * s;
    float m = fmaxf(fmaxf(fabsf(a0), fabsf(a1)), fmaxf(fabsf(a2), fabsf(a3)));

    #pragma unroll
    for (int i = 1; i < 64; i <<= 1)
        m = fmaxf(m, __shfl_xor(m, i));

    __shared__ float wmax[4];
    if ((t & 63) == 0) wmax[t >> 6] = m;
    __syncthreads();
    m = fmaxf(fmaxf(wmax[0], wmax[1]), fmaxf(wmax[2], wmax[3]));

    const float wsc = m / QMAXF;

    int q0 = (int)rintf(a0 / wsc);
    int q1 = (int)rintf(a1 / wsc);
    int q2 = (int)rintf(a2 / wsc);
    int q3 = (int)rintf(a3 / wsc);
    int packed = (q0 & 255) | ((q1 & 255) << 8) | ((q2 & 255) << 16) | ((q3 & 255) << 24);
    reinterpret_cast<int*>(qw)[row * 256 + t] = packed;

    if (t == 0) wscale[row] = wsc;
}

// ---------------------------------------------------------------------------
// Activation quantization (BW floor ~24 us). Nontemporal x read: x is dead
// after this pass; R13 measured gemm FETCH=21MB (xq/qw cache-resident).
// ---------------------------------------------------------------------------
__global__ __launch_bounds__(256) void quant_x_kernel(
    const float* __restrict__ x, const float* __restrict__ act_scale,
    signed char* __restrict__ xq)
{
    const float s = act_scale[0];
    const size_t i = ((size_t)blockIdx.x * 256 + threadIdx.x) * 4;
    f32x4 v = __builtin_nontemporal_load(reinterpret_cast<const f32x4*>(x + i));
    int q0 = (int)rintf(fminf(fmaxf(v.x / s, -QMAXF), QMAXF));
    int q1 = (int)rintf(fminf(fmaxf(v.y / s, -QMAXF), QMAXF));
    int q2 = (int)rintf(fminf(fmaxf(v.z / s, -QMAXF), QMAXF));
    int q3 = (int)rintf(fminf(fmaxf(v.w / s, -QMAXF), QMAXF));
    int packed = (q0 & 255) | ((q1 & 255) << 8) | ((q2 & 255) << 16) | ((q3 & 255) << 24);
    reinterpret_cast<int*>(xq)[i >> 2] = packed;
}

// ---------------------------------------------------------------------------
// int8 GEMM — R17's measured-best K-loop (256x256, 8 waves, BK=128, 8-phase
// counted-vmcnt, slot^(row&7) swizzle, XCD swizzle) with SWAPPED MFMA
// operands: mfma(Bfrag, Afrag, acc) computes C^T, so the accumulator layout
// becomes acc[reg] = C[m=lrow][n = nf*16 + ks*4 + reg] — 4 consecutive
// columns per lane -> epilogue is 32 global_store_dwordx4 (was 128 scalar),
// each 4-lane ks-cluster writing 64 contiguous bytes per row. No LDS, no
// barriers, no transpose (R18's LDS-transpose caused 145-154MB write
// amplification from 64B-strided 16B chunks — reverted).
// Operand-layout symmetry justification: LDA and LDB already use the
// IDENTICAL load pattern for xq-rows (A operand) and qw-rows (B operand);
// passing results verify the two fragment layouts are symmetric, so the
// swap is interpretation-only.
// ---------------------------------------------------------------------------
#define BM 256
#define BN 256
#define BKB 128
#define NTILES 8   // K / BKB

__global__ __launch_bounds__(512, 2) void gemm_i8_kernel(
    const signed char* __restrict__ xq, const signed char* __restrict__ qw,
    const float* __restrict__ wscale, const float* __restrict__ bias,
    float* __restrict__ out, int M)
{
    const int K = 1024, N = 1024;
    __shared__ __align__(16) signed char lds[2 * 2 * 2 * 16384]; // 128 KiB

    const int t    = threadIdx.x;
    const int lane = t & 63;
    const int w    = t >> 6;
    const int wr   = w >> 2;
    const int wc   = w & 3;
    const int lrow = lane & 15;
    const int ks   = lane >> 4;
    const int r8   = lane >> 3;
    const int sl   = lane & 7;

    const int nwg = gridDim.x;
    const int cpx = nwg >> 3;
    const int bid = blockIdx.x;
    const int swz = (bid & 7) * cpx + (bid >> 3);
    const int m0 = (swz >> 2) * BM;
    const int n0 = (swz & 3) * BN;

    // dequant constants for the transposed acc layout: n = nf*16 + ks*4 + r
    float wsv[4][4], bv[4][4];
    #pragma unroll
    for (int nf = 0; nf < 4; ++nf)
        #pragma unroll
        for (int r = 0; r < 4; ++r) {
            const int gn = n0 + wc * 64 + nf * 16 + ks * 4 + r;
            wsv[nf][r] = wscale[gn];
            bv[nf][r]  = bias[gn];
        }

    i32x4 acc[8][4] = {};
    i32x4 Ar[4][2];
    i32x4 Br[2][2][2];

    auto STAGE = [&](int kt, int ab, int h) {
        const signed char* g = ab ? qw : xq;
        const int grow0 = (ab ? n0 : m0) + h * 128;
        signed char* lb = lds + (((kt & 1) * 2 + ab) * 2 + h) * 16384;
        #pragma unroll
        for (int j = 0; j < 2; ++j) {
            const int row = (j * 8 + w) * 8 + r8;
            const signed char* src =
                g + (size_t)(grow0 + row) * K + kt * BKB + ((sl ^ r8) << 4);
            __builtin_amdgcn_global_load_lds(
                (const __attribute__((address_space(1))) void*)src,
                (__attribute__((address_space(3))) void*)(lb + ((j * 8 + w) * 64 + lane) * 16),
                16, 0, 0);
        }
    };

    auto LDA = [&](int buf, int mh, i32x4 A[4][2]) {
        const signed char* base = lds + ((buf * 2 + 0) * 2 + wr) * 16384;
        #pragma unroll
        for (int mf = 0; mf < 4; ++mf) {
            const int row = mh * 64 + mf * 16 + lrow;
            #pragma unroll
            for (int kk = 0; kk < 2; ++kk) {
                const int slot = (kk * 4 + ks) ^ (lrow & 7);
                A[mf][kk] = *reinterpret_cast<const i32x4*>(base + row * 128 + slot * 16);
            }
        }
    };
    auto LDB = [&](int buf, int nh, i32x4 B[2][2]) {
        const signed char* base = lds + ((buf * 2 + 1) * 2 + (wc >> 1)) * 16384;
        #pragma unroll
        for (int nf = 0; nf < 2; ++nf) {
            const int row = (wc & 1) * 64 + nh * 32 + nf * 16 + lrow;
            #pragma unroll
            for (int kk = 0; kk < 2; ++kk) {
                const int slot = (kk * 4 + ks) ^ (lrow & 7);
                B[nf][kk] = *reinterpret_cast<const i32x4*>(base + row * 128 + slot * 16);
            }
        }
    };
    // SWAPPED operands: D = Bfrag * Afrag -> acc holds C^T fragment:
    // acc[mh*4+mf][nh*2+nf][r] = C[m=...+lrow][n=...+(nh*2+nf)*16 + ks*4 + r]
    auto MM = [&](int mh, int nh, i32x4 A[4][2], i32x4 B[2][2]) {
        __builtin_amdgcn_s_setprio(1);
        #pragma unroll
        for (int mf = 0; mf < 4; ++mf)
            #pragma unroll
            for (int nf = 0; nf < 2; ++nf)
                #pragma unroll
                for (int kk = 0; kk < 2; ++kk)
                    acc[mh * 4 + mf][nh * 2 + nf] = __builtin_amdgcn_mfma_i32_16x16x64_i8(
                        B[nf][kk], A[mf][kk], acc[mh * 4 + mf][nh * 2 + nf], 0, 0, 0);
        __builtin_amdgcn_s_setprio(0);
    };

    // ---- prologue ----
    STAGE(0, 1, 0); STAGE(0, 1, 1); STAGE(0, 0, 0); STAGE(0, 0, 1);
    STAGE(1, 1, 0); STAGE(1, 1, 1);
    asm volatile("s_waitcnt vmcnt(4)" ::: "memory");
    BAR();

    #pragma unroll
    for (int it = 0; it < NTILES / 2; ++it) {
        const int T = 2 * it;
        // P1
        LDA(0, 0, Ar); LDB(0, 0, Br[0]);
        STAGE(T + 1, 0, 0);
        BAR(); LGKM0();
        MM(0, 0, Ar, Br[0]);
        BAR();
        // P2
        LDB(0, 1, Br[1]);
        STAGE(T + 1, 0, 1);
        BAR(); LGKM0();
        MM(0, 1, Ar, Br[1]);
        BAR();
        // P3
        LDA(0, 1, Ar);
        if (T + 2 < NTILES) STAGE(T + 2, 1, 0);
        BAR(); LGKM0();
        MM(1, 0, Ar, Br[0]);
        BAR();
        // P4
        if (T + 2 < NTILES) STAGE(T + 2, 1, 1);
        MM(1, 1, Ar, Br[1]);
        if (T + 2 < NTILES) { asm volatile("s_waitcnt vmcnt(4)" ::: "memory"); }
        else                { asm volatile("s_waitcnt vmcnt(0)" ::: "memory"); }
        BAR();
        // P5
        LDA(1, 0, Ar); LDB(1, 0, Br[0]);
        if (T + 2 < NTILES) STAGE(T + 2, 0, 0);
        BAR(); LGKM0();
        MM(0, 0, Ar, Br[0]);
        BAR();
        // P6
        LDB(1, 1, Br[1]);
        if (T + 2 < NTILES) STAGE(T + 2, 0, 1);
        BAR(); LGKM0();
        MM(0, 1, Ar, Br[1]);
        BAR();
        // P7
        LDA(1, 1, Ar);
        if (T + 3 < NTILES) STAGE(T + 3, 1, 0);
        BAR(); LGKM0();
        MM(1, 0, Ar, Br[0]);
        BAR();
        // P8
        if (T + 3 < NTILES) STAGE(T + 3, 1, 1);
        MM(1, 1, Ar, Br[1]);
        if (T + 3 < NTILES) { asm volatile("s_waitcnt vmcnt(4)" ::: "memory"); }
        BAR();
    }

    // ---- epilogue: dequant + bias; one dwordx4 per fragment ----
    // lane stores C[m0+wr*128+mf*16+lrow][n0+wc*64+nf*16+ks*4 .. +3]:
    // 4-lane ks-cluster per row covers 64 contiguous bytes (full segments).
    #pragma unroll
    for (int mf = 0; mf < 8; ++mf) {
        float* orow = out + (size_t)(m0 + wr * 128 + mf * 16 + lrow) * N
                          + n0 + wc * 64 + ks * 4;
        #pragma unroll
        for (int nf = 0; nf < 4; ++nf) {
            f32x4 o;
            #pragma unroll
            for (int r = 0; r < 4; ++r)
                o[r] = (float)acc[mf][nf][r] * wsv[nf][r] + bv[nf][r];
            *reinterpret_cast<f32x4*>(orow + nf * 16) = o;
        }
    }
}

// ---------------------------------------------------------------------------
extern "C" void kernel_launch(void* const* d_in, const int* in_sizes, int n_in,
                              void* d_out, int out_size, void* d_ws, size_t ws_size,
                              hipStream_t stream)
{
    const float* x         = (const float*)d_in[0];
    const float* weight    = (const float*)d_in[1];
    const float* bias      = (const float*)d_in[2];
    const float* act_scale = (const float*)d_in[3];
    float* out             = (float*)d_out;

    const int K = 1024;
    const int N = 1024;
    const int M = in_sizes[0] / K;   // 32768

    // workspace: qw (N*K int8) | wscale (N f32, padded) | xq (M*K int8)
    char* wsb = (char*)d_ws;
    signed char* qw  = (signed char*)wsb;
    float*       wsc = (float*)(wsb + (size_t)N * K);
    signed char* xq  = (signed char*)(wsb + (size_t)N * K + 4096);

    quant_w_kernel<<<N, 256, 0, stream>>>(weight, act_scale, qw, wsc);
    quant_x_kernel<<<(int)(((size_t)M * K) / 1024), 256, 0, stream>>>(x, act_scale, xq);

    const int grid = (M / BM) * (N / BN);   // 512, divisible by 8
    gemm_i8_kernel<<<grid, 512, 0, stream>>>(xq, qw, wsc, bias, out, M);
}

// Round 20
// 87.600 us; speedup vs baseline: 1.3039x; 1.3039x over previous
//
#include <hip/hip_runtime.h>

typedef int   i32x4 __attribute__((ext_vector_type(4)));
typedef float f32x4 __attribute__((ext_vector_type(4)));

#define QMAXF 127.0f
#define BAR()   __builtin_amdgcn_s_barrier()
#define LGKM0() asm volatile("s_waitcnt lgkmcnt(0)" ::: "memory")

// ---------------------------------------------------------------------------
// Weight quantization: one block per output row (cout). ~2 us. Proven R3-R19.
// ---------------------------------------------------------------------------
__global__ __launch_bounds__(256) void quant_w_kernel(
    const float* __restrict__ w, const float* __restrict__ act_scale,
    signed char* __restrict__ qw, float* __restrict__ wscale)
{
    const int row = blockIdx.x;
    const int t   = threadIdx.x;
    const float s = act_scale[0];

    float4 v = *reinterpret_cast<const float4*>(w + (size_t)row * 1024 + t * 4);
    float a0 = v.x * s, a1 = v.y * s, a2 = v.z * s, a3 = v.w * s;
    float m = fmaxf(fmaxf(fabsf(a0), fabsf(a1)), fmaxf(fabsf(a2), fabsf(a3)));

    #pragma unroll
    for (int i = 1; i < 64; i <<= 1)
        m = fmaxf(m, __shfl_xor(m, i));

    __shared__ float wmax[4];
    if ((t & 63) == 0) wmax[t >> 6] = m;
    __syncthreads();
    m = fmaxf(fmaxf(wmax[0], wmax[1]), fmaxf(wmax[2], wmax[3]));

    const float wsc = m / QMAXF;

    int q0 = (int)rintf(a0 / wsc);
    int q1 = (int)rintf(a1 / wsc);
    int q2 = (int)rintf(a2 / wsc);
    int q3 = (int)rintf(a3 / wsc);
    int packed = (q0 & 255) | ((q1 & 255) << 8) | ((q2 & 255) << 16) | ((q3 & 255) << 24);
    reinterpret_cast<int*>(qw)[row * 256 + t] = packed;

    if (t == 0) wscale[row] = wsc;
}

// ---------------------------------------------------------------------------
// Activation quantization (BW floor ~24 us). Nontemporal x read: x is dead
// after this pass; R13 measured gemm FETCH=21MB (xq/qw cache-resident).
// ---------------------------------------------------------------------------
__global__ __launch_bounds__(256) void quant_x_kernel(
    const float* __restrict__ x, const float* __restrict__ act_scale,
    signed char* __restrict__ xq)
{
    const float s = act_scale[0];
    const size_t i = ((size_t)blockIdx.x * 256 + threadIdx.x) * 4;
    f32x4 v = __builtin_nontemporal_load(reinterpret_cast<const f32x4*>(x + i));
    int q0 = (int)rintf(fminf(fmaxf(v.x / s, -QMAXF), QMAXF));
    int q1 = (int)rintf(fminf(fmaxf(v.y / s, -QMAXF), QMAXF));
    int q2 = (int)rintf(fminf(fmaxf(v.z / s, -QMAXF), QMAXF));
    int q3 = (int)rintf(fminf(fmaxf(v.w / s, -QMAXF), QMAXF));
    int packed = (q0 & 255) | ((q1 & 255) << 8) | ((q2 & 255) << 16) | ((q3 & 255) << 24);
    reinterpret_cast<int*>(xq)[i >> 2] = packed;
}

// ---------------------------------------------------------------------------
// int8 GEMM — R17's measured-best K-loop + R19's swapped-operand C^T layout
// (acc[r] = C[m=lrow][n = nf*16 + ks*4 + r] -> 32 dwordx4 stores, validated
// correct in R19), with the R19 SPILL FIXED: dequant constants are loaded
// AFTER the K-loop (f32x4 from L2-resident wscale/bias) instead of being
// hoisted across it. R19's 32 pre-loop constants pushed VGPR demand past the
// 128 available (256 cap - 128 acc) -> clamp+spill (+82MB WRITE, +43MB
// FETCH, 95us). Post-loop, Ar/Br's 64 regs are dead -> constants fit.
// ---------------------------------------------------------------------------
#define BM 256
#define BN 256
#define BKB 128
#define NTILES 8   // K / BKB

__global__ __launch_bounds__(512, 2) void gemm_i8_kernel(
    const signed char* __restrict__ xq, const signed char* __restrict__ qw,
    const float* __restrict__ wscale, const float* __restrict__ bias,
    float* __restrict__ out, int M)
{
    const int K = 1024, N = 1024;
    __shared__ __align__(16) signed char lds[2 * 2 * 2 * 16384]; // 128 KiB

    const int t    = threadIdx.x;
    const int lane = t & 63;
    const int w    = t >> 6;
    const int wr   = w >> 2;
    const int wc   = w & 3;
    const int lrow = lane & 15;
    const int ks   = lane >> 4;
    const int r8   = lane >> 3;
    const int sl   = lane & 7;

    const int nwg = gridDim.x;
    const int cpx = nwg >> 3;
    const int bid = blockIdx.x;
    const int swz = (bid & 7) * cpx + (bid >> 3);
    const int m0 = (swz >> 2) * BM;
    const int n0 = (swz & 3) * BN;

    i32x4 acc[8][4] = {};
    i32x4 Ar[4][2];
    i32x4 Br[2][2][2];

    auto STAGE = [&](int kt, int ab, int h) {
        const signed char* g = ab ? qw : xq;
        const int grow0 = (ab ? n0 : m0) + h * 128;
        signed char* lb = lds + (((kt & 1) * 2 + ab) * 2 + h) * 16384;
        #pragma unroll
        for (int j = 0; j < 2; ++j) {
            const int row = (j * 8 + w) * 8 + r8;
            const signed char* src =
                g + (size_t)(grow0 + row) * K + kt * BKB + ((sl ^ r8) << 4);
            __builtin_amdgcn_global_load_lds(
                (const __attribute__((address_space(1))) void*)src,
                (__attribute__((address_space(3))) void*)(lb + ((j * 8 + w) * 64 + lane) * 16),
                16, 0, 0);
        }
    };

    auto LDA = [&](int buf, int mh, i32x4 A[4][2]) {
        const signed char* base = lds + ((buf * 2 + 0) * 2 + wr) * 16384;
        #pragma unroll
        for (int mf = 0; mf < 4; ++mf) {
            const int row = mh * 64 + mf * 16 + lrow;
            #pragma unroll
            for (int kk = 0; kk < 2; ++kk) {
                const int slot = (kk * 4 + ks) ^ (lrow & 7);
                A[mf][kk] = *reinterpret_cast<const i32x4*>(base + row * 128 + slot * 16);
            }
        }
    };
    auto LDB = [&](int buf, int nh, i32x4 B[2][2]) {
        const signed char* base = lds + ((buf * 2 + 1) * 2 + (wc >> 1)) * 16384;
        #pragma unroll
        for (int nf = 0; nf < 2; ++nf) {
            const int row = (wc & 1) * 64 + nh * 32 + nf * 16 + lrow;
            #pragma unroll
            for (int kk = 0; kk < 2; ++kk) {
                const int slot = (kk * 4 + ks) ^ (lrow & 7);
                B[nf][kk] = *reinterpret_cast<const i32x4*>(base + row * 128 + slot * 16);
            }
        }
    };
    // SWAPPED operands: D = Bfrag * Afrag -> acc holds C^T fragment (R19-
    // validated): acc[mh*4+mf][nh*2+nf][r] = C[m][n=(nh*2+nf)*16+ks*4+r]
    auto MM = [&](int mh, int nh, i32x4 A[4][2], i32x4 B[2][2]) {
        __builtin_amdgcn_s_setprio(1);
        #pragma unroll
        for (int mf = 0; mf < 4; ++mf)
            #pragma unroll
            for (int nf = 0; nf < 2; ++nf)
                #pragma unroll
                for (int kk = 0; kk < 2; ++kk)
                    acc[mh * 4 + mf][nh * 2 + nf] = __builtin_amdgcn_mfma_i32_16x16x64_i8(
                        B[nf][kk], A[mf][kk], acc[mh * 4 + mf][nh * 2 + nf], 0, 0, 0);
        __builtin_amdgcn_s_setprio(0);
    };

    // ---- prologue ----
    STAGE(0, 1, 0); STAGE(0, 1, 1); STAGE(0, 0, 0); STAGE(0, 0, 1);
    STAGE(1, 1, 0); STAGE(1, 1, 1);
    asm volatile("s_waitcnt vmcnt(4)" ::: "memory");
    BAR();

    #pragma unroll
    for (int it = 0; it < NTILES / 2; ++it) {
        const int T = 2 * it;
        // P1
        LDA(0, 0, Ar); LDB(0, 0, Br[0]);
        STAGE(T + 1, 0, 0);
        BAR(); LGKM0();
        MM(0, 0, Ar, Br[0]);
        BAR();
        // P2
        LDB(0, 1, Br[1]);
        STAGE(T + 1, 0, 1);
        BAR(); LGKM0();
        MM(0, 1, Ar, Br[1]);
        BAR();
        // P3
        LDA(0, 1, Ar);
        if (T + 2 < NTILES) STAGE(T + 2, 1, 0);
        BAR(); LGKM0();
        MM(1, 0, Ar, Br[0]);
        BAR();
        // P4
        if (T + 2 < NTILES) STAGE(T + 2, 1, 1);
        MM(1, 1, Ar, Br[1]);
        if (T + 2 < NTILES) { asm volatile("s_waitcnt vmcnt(4)" ::: "memory"); }
        else                { asm volatile("s_waitcnt vmcnt(0)" ::: "memory"); }
        BAR();
        // P5
        LDA(1, 0, Ar); LDB(1, 0, Br[0]);
        if (T + 2 < NTILES) STAGE(T + 2, 0, 0);
        BAR(); LGKM0();
        MM(0, 0, Ar, Br[0]);
        BAR();
        // P6
        LDB(1, 1, Br[1]);
        if (T + 2 < NTILES) STAGE(T + 2, 0, 1);
        BAR(); LGKM0();
        MM(0, 1, Ar, Br[1]);
        BAR();
        // P7
        LDA(1, 1, Ar);
        if (T + 3 < NTILES) STAGE(T + 3, 1, 0);
        BAR(); LGKM0();
        MM(1, 0, Ar, Br[0]);
        BAR();
        // P8
        if (T + 3 < NTILES) STAGE(T + 3, 1, 1);
        MM(1, 1, Ar, Br[1]);
        if (T + 3 < NTILES) { asm volatile("s_waitcnt vmcnt(4)" ::: "memory"); }
        BAR();
    }

    // ---- epilogue: constants loaded HERE (Ar/Br dead -> regs free) ----
    const int gnb = n0 + wc * 64 + ks * 4;   // 16B-aligned
    f32x4 ws4[4], bv4[4];
    #pragma unroll
    for (int nf = 0; nf < 4; ++nf) {
        ws4[nf] = *reinterpret_cast<const f32x4*>(&wscale[gnb + nf * 16]);
        bv4[nf] = *reinterpret_cast<const f32x4*>(&bias[gnb + nf * 16]);
    }
    // lane stores C[m0+wr*128+mf*16+lrow][gnb+nf*16 .. +3] as dwordx4:
    // 4-lane ks-cluster per row covers 64 contiguous bytes.
    #pragma unroll
    for (int mf = 0; mf < 8; ++mf) {
        float* orow = out + (size_t)(m0 + wr * 128 + mf * 16 + lrow) * N + gnb;
        #pragma unroll
        for (int nf = 0; nf < 4; ++nf) {
            f32x4 o;
            #pragma unroll
            for (int r = 0; r < 4; ++r)
                o[r] = (float)acc[mf][nf][r] * ws4[nf][r] + bv4[nf][r];
            *reinterpret_cast<f32x4*>(orow + nf * 16) = o;
        }
    }
}

// ---------------------------------------------------------------------------
extern "C" void kernel_launch(void* const* d_in, const int* in_sizes, int n_in,
                              void* d_out, int out_size, void* d_ws, size_t ws_size,
                              hipStream_t stream)
{
    const float* x         = (const float*)d_in[0];
    const float* weight    = (const float*)d_in[1];
    const float* bias      = (const float*)d_in[2];
    const float* act_scale = (const float*)d_in[3];
    float* out             = (float*)d_out;

    const int K = 1024;
    const int N = 1024;
    const int M = in_sizes[0] / K;   // 32768

    // workspace: qw (N*K int8) | wscale (N f32, padded) | xq (M*K int8)
    char* wsb = (char*)d_ws;
    signed char* qw  = (signed char*)wsb;
    float*       wsc = (float*)(wsb + (size_t)N * K);
    signed char* xq  = (signed char*)(wsb + (size_t)N * K + 4096);

    quant_w_kernel<<<N, 256, 0, stream>>>(weight, act_scale, qw, wsc);
    quant_x_kernel<<<(int)(((size_t)M * K) / 1024), 256, 0, stream>>>(x, act_scale, xq);

    const int grid = (M / BM) * (N / BN);   // 512, divisible by 8
    gemm_i8_kernel<<<grid, 512, 0, stream>>>(xq, qw, wsc, bias, out, M);
}

// Round 21
// 81.812 us; speedup vs baseline: 1.3962x; 1.0707x over previous
//
#include <hip/hip_runtime.h>

typedef int   i32x4 __attribute__((ext_vector_type(4)));
typedef float f32x4 __attribute__((ext_vector_type(4)));

#define QMAXF 127.0f
#define BAR()   __builtin_amdgcn_s_barrier()
#define LGKM0() asm volatile("s_waitcnt lgkmcnt(0)" ::: "memory")

// ---------------------------------------------------------------------------
// Weight quantization: one block per output row (cout). ~2 us. Proven R3-R20.
// ---------------------------------------------------------------------------
__global__ __launch_bounds__(256) void quant_w_kernel(
    const float* __restrict__ w, const float* __restrict__ act_scale,
    signed char* __restrict__ qw, float* __restrict__ wscale)
{
    const int row = blockIdx.x;
    const int t   = threadIdx.x;
    const float s = act_scale[0];

    float4 v = *reinterpret_cast<const float4*>(w + (size_t)row * 1024 + t * 4);
    float a0 = v.x * s, a1 = v.y * s, a2 = v.z * s, a3 = v.w * s;
    float m = fmaxf(fmaxf(fabsf(a0), fabsf(a1)), fmaxf(fabsf(a2), fabsf(a3)));

    #pragma unroll
    for (int i = 1; i < 64; i <<= 1)
        m = fmaxf(m, __shfl_xor(m, i));

    __shared__ float wmax[4];
    if ((t & 63) == 0) wmax[t >> 6] = m;
    __syncthreads();
    m = fmaxf(fmaxf(wmax[0], wmax[1]), fmaxf(wmax[2], wmax[3]));

    const float wsc = m / QMAXF;

    int q0 = (int)rintf(a0 / wsc);
    int q1 = (int)rintf(a1 / wsc);
    int q2 = (int)rintf(a2 / wsc);
    int q3 = (int)rintf(a3 / wsc);
    int packed = (q0 & 255) | ((q1 & 255) << 8) | ((q2 & 255) << 16) | ((q3 & 255) << 24);
    reinterpret_cast<int*>(qw)[row * 256 + t] = packed;

    if (t == 0) wscale[row] = wsc;
}

// ---------------------------------------------------------------------------
// Activation quantization (BW floor ~24 us). Nontemporal x read: x is dead
// after this pass; R13 measured gemm FETCH=21MB (xq/qw cache-resident).
// ---------------------------------------------------------------------------
__global__ __launch_bounds__(256) void quant_x_kernel(
    const float* __restrict__ x, const float* __restrict__ act_scale,
    signed char* __restrict__ xq)
{
    const float s = act_scale[0];
    const size_t i = ((size_t)blockIdx.x * 256 + threadIdx.x) * 4;
    f32x4 v = __builtin_nontemporal_load(reinterpret_cast<const f32x4*>(x + i));
    int q0 = (int)rintf(fminf(fmaxf(v.x / s, -QMAXF), QMAXF));
    int q1 = (int)rintf(fminf(fmaxf(v.y / s, -QMAXF), QMAXF));
    int q2 = (int)rintf(fminf(fmaxf(v.z / s, -QMAXF), QMAXF));
    int q3 = (int)rintf(fminf(fmaxf(v.w / s, -QMAXF), QMAXF));
    int packed = (q0 & 255) | ((q1 & 255) << 8) | ((q2 & 255) << 16) | ((q3 & 255) << 24);
    reinterpret_cast<int*>(xq)[i >> 2] = packed;
}

// ---------------------------------------------------------------------------
// int8 GEMM — byte-exact revert to the measured-best R17 kernel (81.5 us
// total): 256x256 tile, 8 waves, BK=128, 8-phase counted-vmcnt schedule,
// slot^(row&7) swizzle via pre-swizzled global source, XCD-aware bijective
// swizzle, hoisted wsv/bv (4+4 scalars — fits), SCALAR epilogue stores
// (measured optimal: R18 LDS-transpose +26us, R19 hoisted-vec spill +33us,
// R20 post-loop-vec +6us — per-instruction 4rows x 16 consecutive floats
// already forms full 64B segments).
// ---------------------------------------------------------------------------
#define BM 256
#define BN 256
#define BKB 128
#define NTILES 8   // K / BKB

__global__ __launch_bounds__(512, 2) void gemm_i8_kernel(
    const signed char* __restrict__ xq, const signed char* __restrict__ qw,
    const float* __restrict__ wscale, const float* __restrict__ bias,
    float* __restrict__ out, int M)
{
    const int K = 1024, N = 1024;
    __shared__ __align__(16) signed char lds[2 * 2 * 2 * 16384]; // 128 KiB

    const int t    = threadIdx.x;
    const int lane = t & 63;
    const int w    = t >> 6;
    const int wr   = w >> 2;
    const int wc   = w & 3;
    const int lrow = lane & 15;
    const int ks   = lane >> 4;
    const int r8   = lane >> 3;
    const int sl   = lane & 7;

    const int nwg = gridDim.x;
    const int cpx = nwg >> 3;
    const int bid = blockIdx.x;
    const int swz = (bid & 7) * cpx + (bid >> 3);
    const int m0 = (swz >> 2) * BM;
    const int n0 = (swz & 3) * BN;

    // epilogue constants hoisted (8 scalars/thread — R17-measured OK)
    float wsv[4], bv[4];
    int   gnc[4];
    #pragma unroll
    for (int nf = 0; nf < 4; ++nf) {
        const int gn = n0 + wc * 64 + nf * 16 + lrow;
        gnc[nf] = gn;
        wsv[nf] = wscale[gn];
        bv[nf]  = bias[gn];
    }

    i32x4 acc[8][4] = {};
    i32x4 Ar[4][2];
    i32x4 Br[2][2][2];

    auto STAGE = [&](int kt, int ab, int h) {
        const signed char* g = ab ? qw : xq;
        const int grow0 = (ab ? n0 : m0) + h * 128;
        signed char* lb = lds + (((kt & 1) * 2 + ab) * 2 + h) * 16384;
        #pragma unroll
        for (int j = 0; j < 2; ++j) {
            const int row = (j * 8 + w) * 8 + r8;
            const signed char* src =
                g + (size_t)(grow0 + row) * K + kt * BKB + ((sl ^ r8) << 4);
            __builtin_amdgcn_global_load_lds(
                (const __attribute__((address_space(1))) void*)src,
                (__attribute__((address_space(3))) void*)(lb + ((j * 8 + w) * 64 + lane) * 16),
                16, 0, 0);
        }
    };

    auto LDA = [&](int buf, int mh, i32x4 A[4][2]) {
        const signed char* base = lds + ((buf * 2 + 0) * 2 + wr) * 16384;
        #pragma unroll
        for (int mf = 0; mf < 4; ++mf) {
            const int row = mh * 64 + mf * 16 + lrow;
            #pragma unroll
            for (int kk = 0; kk < 2; ++kk) {
                const int slot = (kk * 4 + ks) ^ (lrow & 7);
                A[mf][kk] = *reinterpret_cast<const i32x4*>(base + row * 128 + slot * 16);
            }
        }
    };
    auto LDB = [&](int buf, int nh, i32x4 B[2][2]) {
        const signed char* base = lds + ((buf * 2 + 1) * 2 + (wc >> 1)) * 16384;
        #pragma unroll
        for (int nf = 0; nf < 2; ++nf) {
            const int row = (wc & 1) * 64 + nh * 32 + nf * 16 + lrow;
            #pragma unroll
            for (int kk = 0; kk < 2; ++kk) {
                const int slot = (kk * 4 + ks) ^ (lrow & 7);
                B[nf][kk] = *reinterpret_cast<const i32x4*>(base + row * 128 + slot * 16);
            }
        }
    };
    auto MM = [&](int mh, int nh, i32x4 A[4][2], i32x4 B[2][2]) {
        __builtin_amdgcn_s_setprio(1);
        #pragma unroll
        for (int mf = 0; mf < 4; ++mf)
            #pragma unroll
            for (int nf = 0; nf < 2; ++nf)
                #pragma unroll
                for (int kk = 0; kk < 2; ++kk)
                    acc[mh * 4 + mf][nh * 2 + nf] = __builtin_amdgcn_mfma_i32_16x16x64_i8(
                        A[mf][kk], B[nf][kk], acc[mh * 4 + mf][nh * 2 + nf], 0, 0, 0);
        __builtin_amdgcn_s_setprio(0);
    };

    // ---- prologue ----
    STAGE(0, 1, 0); STAGE(0, 1, 1); STAGE(0, 0, 0); STAGE(0, 0, 1);
    STAGE(1, 1, 0); STAGE(1, 1, 1);
    asm volatile("s_waitcnt vmcnt(4)" ::: "memory");
    BAR();

    #pragma unroll
    for (int it = 0; it < NTILES / 2; ++it) {
        const int T = 2 * it;
        // P1
        LDA(0, 0, Ar); LDB(0, 0, Br[0]);
        STAGE(T + 1, 0, 0);
        BAR(); LGKM0();
        MM(0, 0, Ar, Br[0]);
        BAR();
        // P2
        LDB(0, 1, Br[1]);
        STAGE(T + 1, 0, 1);
        BAR(); LGKM0();
        MM(0, 1, Ar, Br[1]);
        BAR();
        // P3
        LDA(0, 1, Ar);
        if (T + 2 < NTILES) STAGE(T + 2, 1, 0);
        BAR(); LGKM0();
        MM(1, 0, Ar, Br[0]);
        BAR();
        // P4
        if (T + 2 < NTILES) STAGE(T + 2, 1, 1);
        MM(1, 1, Ar, Br[1]);
        if (T + 2 < NTILES) { asm volatile("s_waitcnt vmcnt(4)" ::: "memory"); }
        else                { asm volatile("s_waitcnt vmcnt(0)" ::: "memory"); }
        BAR();
        // P5
        LDA(1, 0, Ar); LDB(1, 0, Br[0]);
        if (T + 2 < NTILES) STAGE(T + 2, 0, 0);
        BAR(); LGKM0();
        MM(0, 0, Ar, Br[0]);
        BAR();
        // P6
        LDB(1, 1, Br[1]);
        if (T + 2 < NTILES) STAGE(T + 2, 0, 1);
        BAR(); LGKM0();
        MM(0, 1, Ar, Br[1]);
        BAR();
        // P7
        LDA(1, 1, Ar);
        if (T + 3 < NTILES) STAGE(T + 3, 1, 0);
        BAR(); LGKM0();
        MM(1, 0, Ar, Br[0]);
        BAR();
        // P8
        if (T + 3 < NTILES) STAGE(T + 3, 1, 1);
        MM(1, 1, Ar, Br[1]);
        if (T + 3 < NTILES) { asm volatile("s_waitcnt vmcnt(4)" ::: "memory"); }
        BAR();
    }

    // ---- epilogue: dequant + bias (scalar stores — measured optimal) ----
    #pragma unroll
    for (int mf = 0; mf < 8; ++mf) {
        #pragma unroll
        for (int r = 0; r < 4; ++r) {
            const int gm = m0 + wr * 128 + mf * 16 + ks * 4 + r;
            float* orow = out + (size_t)gm * N;
            #pragma unroll
            for (int nf = 0; nf < 4; ++nf)
                orow[gnc[nf]] = (float)acc[mf][nf][r] * wsv[nf] + bv[nf];
        }
    }
}

// ---------------------------------------------------------------------------
extern "C" void kernel_launch(void* const* d_in, const int* in_sizes, int n_in,
                              void* d_out, int out_size, void* d_ws, size_t ws_size,
                              hipStream_t stream)
{
    const float* x         = (const float*)d_in[0];
    const float* weight    = (const float*)d_in[1];
    const float* bias      = (const float*)d_in[2];
    const float* act_scale = (const float*)d_in[3];
    float* out             = (float*)d_out;

    const int K = 1024;
    const int N = 1024;
    const int M = in_sizes[0] / K;   // 32768

    // workspace: qw (N*K int8) | wscale (N f32, padded) | xq (M*K int8)
    char* wsb = (char*)d_ws;
    signed char* qw  = (signed char*)wsb;
    float*       wsc = (float*)(wsb + (size_t)N * K);
    signed char* xq  = (signed char*)(wsb + (size_t)N * K + 4096);

    quant_w_kernel<<<N, 256, 0, stream>>>(weight, act_scale, qw, wsc);
    quant_x_kernel<<<(int)(((size_t)M * K) / 1024), 256, 0, stream>>>(x, act_scale, xq);

    const int grid = (M / BM) * (N / BN);   // 512, divisible by 8
    gemm_i8_kernel<<<grid, 512, 0, stream>>>(xq, qw, wsc, bias, out, M);
}

// Round 22
// 78.289 us; speedup vs baseline: 1.4590x; 1.0450x over previous
//
#include <hip/hip_runtime.h>

typedef int   i32x4 __attribute__((ext_vector_type(4)));
typedef float f32x4 __attribute__((ext_vector_type(4)));

#define QMAXF 127.0f
#define BAR()   __builtin_amdgcn_s_barrier()
#define LGKM0() asm volatile("s_waitcnt lgkmcnt(0)" ::: "memory")

// ---------------------------------------------------------------------------
// Merged quantization: ONE dispatch.
//   blocks [0, 1024):            weight rows (body identical to proven quant_w)
//   blocks [1024, 1024+M*K/1024): x chunks   (body identical to proven quant_x)
// Saves one serialized dispatch boundary; weight traffic (5 MB) hides under
// the x BW stream (160 MB) instead of serializing ahead of it.
// ---------------------------------------------------------------------------
__global__ __launch_bounds__(256) void quant_fused_kernel(
    const float* __restrict__ w, const float* __restrict__ x,
    const float* __restrict__ act_scale,
    signed char* __restrict__ qw, float* __restrict__ wscale,
    signed char* __restrict__ xq)
{
    const int bid = blockIdx.x;
    const int t   = threadIdx.x;
    const float s = act_scale[0];

    if (bid < 1024) {
        // ---- weight-quant body (proven R3-R21) ----
        const int row = bid;
        float4 v = *reinterpret_cast<const float4*>(w + (size_t)row * 1024 + t * 4);
        float a0 = v.x * s, a1 = v.y * s, a2 = v.z * s, a3 = v.w * s;
        float m = fmaxf(fmaxf(fabsf(a0), fabsf(a1)), fmaxf(fabsf(a2), fabsf(a3)));

        #pragma unroll
        for (int i = 1; i < 64; i <<= 1)
            m = fmaxf(m, __shfl_xor(m, i));

        __shared__ float wmax[4];
        if ((t & 63) == 0) wmax[t >> 6] = m;
        __syncthreads();
        m = fmaxf(fmaxf(wmax[0], wmax[1]), fmaxf(wmax[2], wmax[3]));

        const float wsc = m / QMAXF;

        int q0 = (int)rintf(a0 / wsc);
        int q1 = (int)rintf(a1 / wsc);
        int q2 = (int)rintf(a2 / wsc);
        int q3 = (int)rintf(a3 / wsc);
        int packed = (q0 & 255) | ((q1 & 255) << 8) | ((q2 & 255) << 16) | ((q3 & 255) << 24);
        reinterpret_cast<int*>(qw)[row * 256 + t] = packed;

        if (t == 0) wscale[row] = wsc;
    } else {
        // ---- x-quant body (proven R13-R21, nontemporal read) ----
        const size_t i = ((size_t)(bid - 1024) * 256 + t) * 4;
        f32x4 v = __builtin_nontemporal_load(reinterpret_cast<const f32x4*>(x + i));
        int q0 = (int)rintf(fminf(fmaxf(v.x / s, -QMAXF), QMAXF));
        int q1 = (int)rintf(fminf(fmaxf(v.y / s, -QMAXF), QMAXF));
        int q2 = (int)rintf(fminf(fmaxf(v.z / s, -QMAXF), QMAXF));
        int q3 = (int)rintf(fminf(fmaxf(v.w / s, -QMAXF), QMAXF));
        int packed = (q0 & 255) | ((q1 & 255) << 8) | ((q2 & 255) << 16) | ((q3 & 255) << 24);
        reinterpret_cast<int*>(xq)[i >> 2] = packed;
    }
}

// ---------------------------------------------------------------------------
// int8 GEMM — byte-exact R17/R21 measured-best kernel (81.5/81.8 us total):
// 256x256 tile, 8 waves, BK=128, 8-phase counted-vmcnt schedule,
// slot^(row&7) swizzle via pre-swizzled global source, XCD-aware bijective
// swizzle, hoisted wsv/bv scalars, SCALAR epilogue stores (measured optimal).
// ---------------------------------------------------------------------------
#define BM 256
#define BN 256
#define BKB 128
#define NTILES 8   // K / BKB

__global__ __launch_bounds__(512, 2) void gemm_i8_kernel(
    const signed char* __restrict__ xq, const signed char* __restrict__ qw,
    const float* __restrict__ wscale, const float* __restrict__ bias,
    float* __restrict__ out, int M)
{
    const int K = 1024, N = 1024;
    __shared__ __align__(16) signed char lds[2 * 2 * 2 * 16384]; // 128 KiB

    const int t    = threadIdx.x;
    const int lane = t & 63;
    const int w    = t >> 6;
    const int wr   = w >> 2;
    const int wc   = w & 3;
    const int lrow = lane & 15;
    const int ks   = lane >> 4;
    const int r8   = lane >> 3;
    const int sl   = lane & 7;

    const int nwg = gridDim.x;
    const int cpx = nwg >> 3;
    const int bid = blockIdx.x;
    const int swz = (bid & 7) * cpx + (bid >> 3);
    const int m0 = (swz >> 2) * BM;
    const int n0 = (swz & 3) * BN;

    // epilogue constants hoisted (8 scalars/thread — measured OK)
    float wsv[4], bv[4];
    int   gnc[4];
    #pragma unroll
    for (int nf = 0; nf < 4; ++nf) {
        const int gn = n0 + wc * 64 + nf * 16 + lrow;
        gnc[nf] = gn;
        wsv[nf] = wscale[gn];
        bv[nf]  = bias[gn];
    }

    i32x4 acc[8][4] = {};
    i32x4 Ar[4][2];
    i32x4 Br[2][2][2];

    auto STAGE = [&](int kt, int ab, int h) {
        const signed char* g = ab ? qw : xq;
        const int grow0 = (ab ? n0 : m0) + h * 128;
        signed char* lb = lds + (((kt & 1) * 2 + ab) * 2 + h) * 16384;
        #pragma unroll
        for (int j = 0; j < 2; ++j) {
            const int row = (j * 8 + w) * 8 + r8;
            const signed char* src =
                g + (size_t)(grow0 + row) * K + kt * BKB + ((sl ^ r8) << 4);
            __builtin_amdgcn_global_load_lds(
                (const __attribute__((address_space(1))) void*)src,
                (__attribute__((address_space(3))) void*)(lb + ((j * 8 + w) * 64 + lane) * 16),
                16, 0, 0);
        }
    };

    auto LDA = [&](int buf, int mh, i32x4 A[4][2]) {
        const signed char* base = lds + ((buf * 2 + 0) * 2 + wr) * 16384;
        #pragma unroll
        for (int mf = 0; mf < 4; ++mf) {
            const int row = mh * 64 + mf * 16 + lrow;
            #pragma unroll
            for (int kk = 0; kk < 2; ++kk) {
                const int slot = (kk * 4 + ks) ^ (lrow & 7);
                A[mf][kk] = *reinterpret_cast<const i32x4*>(base + row * 128 + slot * 16);
            }
        }
    };
    auto LDB = [&](int buf, int nh, i32x4 B[2][2]) {
        const signed char* base = lds + ((buf * 2 + 1) * 2 + (wc >> 1)) * 16384;
        #pragma unroll
        for (int nf = 0; nf < 2; ++nf) {
            const int row = (wc & 1) * 64 + nh * 32 + nf * 16 + lrow;
            #pragma unroll
            for (int kk = 0; kk < 2; ++kk) {
                const int slot = (kk * 4 + ks) ^ (lrow & 7);
                B[nf][kk] = *reinterpret_cast<const i32x4*>(base + row * 128 + slot * 16);
            }
        }
    };
    auto MM = [&](int mh, int nh, i32x4 A[4][2], i32x4 B[2][2]) {
        __builtin_amdgcn_s_setprio(1);
        #pragma unroll
        for (int mf = 0; mf < 4; ++mf)
            #pragma unroll
            for (int nf = 0; nf < 2; ++nf)
                #pragma unroll
                for (int kk = 0; kk < 2; ++kk)
                    acc[mh * 4 + mf][nh * 2 + nf] = __builtin_amdgcn_mfma_i32_16x16x64_i8(
                        A[mf][kk], B[nf][kk], acc[mh * 4 + mf][nh * 2 + nf], 0, 0, 0);
        __builtin_amdgcn_s_setprio(0);
    };

    // ---- prologue ----
    STAGE(0, 1, 0); STAGE(0, 1, 1); STAGE(0, 0, 0); STAGE(0, 0, 1);
    STAGE(1, 1, 0); STAGE(1, 1, 1);
    asm volatile("s_waitcnt vmcnt(4)" ::: "memory");
    BAR();

    #pragma unroll
    for (int it = 0; it < NTILES / 2; ++it) {
        const int T = 2 * it;
        // P1
        LDA(0, 0, Ar); LDB(0, 0, Br[0]);
        STAGE(T + 1, 0, 0);
        BAR(); LGKM0();
        MM(0, 0, Ar, Br[0]);
        BAR();
        // P2
        LDB(0, 1, Br[1]);
        STAGE(T + 1, 0, 1);
        BAR(); LGKM0();
        MM(0, 1, Ar, Br[1]);
        BAR();
        // P3
        LDA(0, 1, Ar);
        if (T + 2 < NTILES) STAGE(T + 2, 1, 0);
        BAR(); LGKM0();
        MM(1, 0, Ar, Br[0]);
        BAR();
        // P4
        if (T + 2 < NTILES) STAGE(T + 2, 1, 1);
        MM(1, 1, Ar, Br[1]);
        if (T + 2 < NTILES) { asm volatile("s_waitcnt vmcnt(4)" ::: "memory"); }
        else                { asm volatile("s_waitcnt vmcnt(0)" ::: "memory"); }
        BAR();
        // P5
        LDA(1, 0, Ar); LDB(1, 0, Br[0]);
        if (T + 2 < NTILES) STAGE(T + 2, 0, 0);
        BAR(); LGKM0();
        MM(0, 0, Ar, Br[0]);
        BAR();
        // P6
        LDB(1, 1, Br[1]);
        if (T + 2 < NTILES) STAGE(T + 2, 0, 1);
        BAR(); LGKM0();
        MM(0, 1, Ar, Br[1]);
        BAR();
        // P7
        LDA(1, 1, Ar);
        if (T + 3 < NTILES) STAGE(T + 3, 1, 0);
        BAR(); LGKM0();
        MM(1, 0, Ar, Br[0]);
        BAR();
        // P8
        if (T + 3 < NTILES) STAGE(T + 3, 1, 1);
        MM(1, 1, Ar, Br[1]);
        if (T + 3 < NTILES) { asm volatile("s_waitcnt vmcnt(4)" ::: "memory"); }
        BAR();
    }

    // ---- epilogue: dequant + bias (scalar stores — measured optimal) ----
    #pragma unroll
    for (int mf = 0; mf < 8; ++mf) {
        #pragma unroll
        for (int r = 0; r < 4; ++r) {
            const int gm = m0 + wr * 128 + mf * 16 + ks * 4 + r;
            float* orow = out + (size_t)gm * N;
            #pragma unroll
            for (int nf = 0; nf < 4; ++nf)
                orow[gnc[nf]] = (float)acc[mf][nf][r] * wsv[nf] + bv[nf];
        }
    }
}

// ---------------------------------------------------------------------------
extern "C" void kernel_launch(void* const* d_in, const int* in_sizes, int n_in,
                              void* d_out, int out_size, void* d_ws, size_t ws_size,
                              hipStream_t stream)
{
    const float* x         = (const float*)d_in[0];
    const float* weight    = (const float*)d_in[1];
    const float* bias      = (const float*)d_in[2];
    const float* act_scale = (const float*)d_in[3];
    float* out             = (float*)d_out;

    const int K = 1024;
    const int N = 1024;
    const int M = in_sizes[0] / K;   // 32768

    // workspace: qw (N*K int8) | wscale (N f32, padded) | xq (M*K int8)
    char* wsb = (char*)d_ws;
    signed char* qw  = (signed char*)wsb;
    float*       wsc = (float*)(wsb + (size_t)N * K);
    signed char* xq  = (signed char*)(wsb + (size_t)N * K + 4096);

    const int qblocks = 1024 + (int)(((size_t)M * K) / 1024);   // 1024 + 32768
    quant_fused_kernel<<<qblocks, 256, 0, stream>>>(weight, x, act_scale, qw, wsc, xq);

    const int grid = (M / BM) * (N / BN);   // 512, divisible by 8
    gemm_i8_kernel<<<grid, 512, 0, stream>>>(xq, qw, wsc, bias, out, M);
}